// Round 2
// baseline (234.896 us; speedup 1.0000x reference)
//
#include <hip/hip_runtime.h>
#include <math.h>

// B=2048, N=8192, fp32. Two-kernel split:
//   K1 (stats): read yp/yt -> rmax, histogram, Newton -> ws[row]={beta,inv_qmax}
//   K2 (epilogue): re-read yp/yt (L3-hot) + Lambda -> q, EMA, store, loss
// Rationale: the fused kernel ran all 2048 blocks in lockstep phases (HBM idle
// during Newton/VALU, VALU idle during loads) and plateaued at 92us vs a ~30us
// memory floor. Two homogeneous streaming kernels remove the phase lockstep.
#define N_COLS 8192
#define BLOCK  256
#define NW     4                   // waves per block
#define F4PT   (N_COLS / BLOCK / 4) // float4 groups per thread = 8
#define NBINS  1024
#define BPL    (NBINS / 64)        // bins per lane in the Newton wave = 16

// d_out[0] must be zeroed every call (harness re-poisons to 0xAA).
__global__ void zero_out_kernel(float* out) {
    if (threadIdx.x == 0 && blockIdx.x == 0) out[0] = 0.0f;
}

// ---------------- K1: per-row stats (rmax, hist, Newton) ----------------
__global__ __launch_bounds__(BLOCK) void stats_kernel(
        const float* __restrict__ y_pred,
        const float* __restrict__ y_true,
        float* __restrict__ ws) {          // ws[2*row]={beta}, ws[2*row+1]={1/qmax}
    __shared__ unsigned int s_hist[NBINS];
    __shared__ float s_wmax[NW];

    const int row  = blockIdx.x;
    const int tid  = threadIdx.x;
    const int lane = tid & 63;
    const int wid  = tid >> 6;
    const size_t base = (size_t)row * N_COLS;
    const float4* yp4 = (const float4*)(y_pred + base);  // rows are 32KB-aligned
    const float4* yt4 = (const float4*)(y_true + base);

    // ---- pass 1: residuals in registers (float4 layout), local max ----
    float4 r[F4PT];
    float rmax = 0.0f;
    #pragma unroll
    for (int j = 0; j < F4PT; ++j) {
        const int g = j * BLOCK + tid;       // coalesced float4
        float4 a = yt4[g];
        float4 b = yp4[g];
        float4 rv;
        rv.x = fabsf(a.x - b.x); rv.y = fabsf(a.y - b.y);
        rv.z = fabsf(a.z - b.z); rv.w = fabsf(a.w - b.w);
        r[j] = rv;
        rmax = fmaxf(rmax, fmaxf(fmaxf(rv.x, rv.y), fmaxf(rv.z, rv.w)));
    }
    #pragma unroll
    for (int m = 32; m >= 1; m >>= 1) rmax = fmaxf(rmax, __shfl_xor(rmax, m, 64));
    if (lane == 0) s_wmax[wid] = rmax;
    #pragma unroll
    for (int i = 0; i < NBINS / BLOCK; ++i) s_hist[tid + i * BLOCK] = 0u;
    __syncthreads();                          // hist zeroed + s_wmax visible
    rmax = fmaxf(fmaxf(s_wmax[0], s_wmax[1]), fmaxf(s_wmax[2], s_wmax[3]));
    rmax = fmaxf(rmax, 1e-8f);

    // ---- pass 2: histogram of r (count only; bin centers are the proxy) ----
    const float hscale = (float)NBINS / rmax;
    #pragma unroll
    for (int j = 0; j < F4PT; ++j) {
        unsigned bx = min((unsigned)(r[j].x * hscale), (unsigned)(NBINS - 1));
        unsigned by = min((unsigned)(r[j].y * hscale), (unsigned)(NBINS - 1));
        unsigned bz = min((unsigned)(r[j].z * hscale), (unsigned)(NBINS - 1));
        unsigned bw = min((unsigned)(r[j].w * hscale), (unsigned)(NBINS - 1));
        atomicAdd(&s_hist[bx], 1u);
        atomicAdd(&s_hist[by], 1u);
        atomicAdd(&s_hist[bz], 1u);
        atomicAdd(&s_hist[bw], 1u);
    }
    __syncthreads();                          // histogram complete

    // ---- Newton on the 1024-bin histogram: wave 0 only, no barriers ----
    // Bins equally spaced: exp(u_{b+64}) = exp(u_b)*exp(64d); running products
    // replace 2 exps/bin with 2 muls/bin.
    if (wid == 0) {
        float eps = rmax / (logf(2.0f * (float)N_COLS) + 1e-8f);
        const float binw = rmax * (1.0f / (float)NBINS);
        const float sc2  = 0.5f / (float)N_COLS;   // 2^-14 exact
        for (int it = 0; it < 20; ++it) {
            const float inv_eps = __builtin_amdgcn_rcpf(fmaxf(eps, 1e-8f));
            const float d   = binw * inv_eps;       // per-bin u step
            const float d64 = 64.0f * d;            // per-k u step (this lane)
            float u  = ((float)lane + 0.5f) * d;    // u of bin 'lane'
            float e  = __expf(u);                   // running exp(+u)
            float ei = __expf(-u);                  // running exp(-u)
            const float E  = __expf(d64);
            const float Ei = __expf(-d64);
            float fs = 0.0f, gs = 0.0f;     // sum n*(e-ei), sum n*(e+ei)*u
            #pragma unroll
            for (int k = 0; k < BPL; ++k) {
                const float n = (float)s_hist[lane + 64 * k]; // conflict-free
                fs = fmaf(n, e - ei, fs);
                gs = fmaf(n * (e + ei), u, gs);
                e *= E; ei *= Ei; u += d64;
            }
            #pragma unroll
            for (int m2 = 32; m2 >= 1; m2 >>= 1) {
                fs += __shfl_xor(fs, m2, 64);
                gs += __shfl_xor(gs, m2, 64);
            }
            float val  = fmaf(fs, sc2, -1.0f);          // mean(sinh)-1
            float grad = -(gs * sc2) * inv_eps;         // mean(cosh*(-u/eps))
            float delta = val * __builtin_amdgcn_rcpf(grad - 1e-8f);
            eps -= delta;
            if (fabsf(delta) <= 1e-5f * eps) break;     // wave-uniform
        }
        eps = fmaxf(eps, 1e-8f);
        const float beta = 1.0f / (eps + 1e-6f);
        const float um = beta * rmax;                   // qmax = sinh(beta*rmax)
        const float qmax = 0.5f * (__expf(um) - __expf(-um));
        if (lane == 0) {
            ws[2 * row]     = beta;
            ws[2 * row + 1] = 1.0f / (qmax + 1e-20f);
        }
    }
}

// ---------------- K2: streaming epilogue ----------------
__global__ __launch_bounds__(BLOCK) void epilogue_kernel(
        const float* __restrict__ y_pred,
        const float* __restrict__ y_true,
        const float* __restrict__ Lambda,
        const float* __restrict__ ws,
        float* __restrict__ out,      // out[0]=loss, out[1..]=updated_Lambda
        float inv_total) {
    __shared__ float s_part[NW];

    const int row  = blockIdx.x;
    const int tid  = threadIdx.x;
    const int lane = tid & 63;
    const int wid  = tid >> 6;
    const size_t base = (size_t)row * N_COLS;
    const float4* yp4 = (const float4*)(y_pred + base);
    const float4* yt4 = (const float4*)(y_true + base);
    const float4* lam4 = (const float4*)(Lambda + base);
    const float beta     = ws[2 * row];       // uniform -> s_load
    const float inv_qmax = ws[2 * row + 1];

    // residuals first (16-deep load MLP), bit-identical to K1's pass 1
    float4 r[F4PT];
    #pragma unroll
    for (int j = 0; j < F4PT; ++j) {
        const int g = j * BLOCK + tid;
        float4 a = yt4[g];
        float4 b = yp4[g];
        float4 rv;
        rv.x = fabsf(a.x - b.x); rv.y = fabsf(a.y - b.y);
        rv.z = fabsf(a.z - b.z); rv.w = fabsf(a.w - b.w);
        r[j] = rv;
    }

    float* outw = out + 1 + base;   // 4B-aligned only -> scalar stores
    float s_loss = 0.0f;
    #pragma unroll
    for (int j = 0; j < F4PT; ++j) {
        const int g = j * BLOCK + tid;
        float4 L = lam4[g];
        float rr[4] = {r[j].x, r[j].y, r[j].z, r[j].w};
        float LL[4] = {L.x, L.y, L.z, L.w};
        #pragma unroll
        for (int c = 0; c < 4; ++c) {
            float u  = beta * rr[c];
            float q  = 0.5f * (__expf(u) - __expf(-u));
            float lam_it = fmaf(0.9f, q * inv_qmax, 0.1f);  // PHI, 1-PHI
            float uL = fmaf(0.99f, LL[c], 0.1f * lam_it);   // GAMMA, ETA
            outw[(size_t)g * 4 + c] = uL;
            float t = uL * rr[c];
            s_loss = fmaf(t, t, s_loss);
        }
    }
    #pragma unroll
    for (int m = 32; m >= 1; m >>= 1) s_loss += __shfl_xor(s_loss, m, 64);
    if (lane == 0) s_part[wid] = s_loss;
    __syncthreads();
    if (tid == 0) {
        float tot = (s_part[0] + s_part[1]) + (s_part[2] + s_part[3]);
        atomicAdd(out, tot * inv_total);
    }
}

extern "C" void kernel_launch(void* const* d_in, const int* in_sizes, int n_in,
                              void* d_out, int out_size, void* d_ws, size_t ws_size,
                              hipStream_t stream) {
    const float* y_pred = (const float*)d_in[0];
    const float* y_true = (const float*)d_in[1];
    const float* Lambda = (const float*)d_in[2];
    float* out = (float*)d_out;
    float* ws  = (float*)d_ws;                // needs 2*B floats = 16KB

    const int total = in_sizes[0];            // B * N
    const int B = total / N_COLS;
    const float inv_total = 1.0f / (float)total;

    hipLaunchKernelGGL(zero_out_kernel, dim3(1), dim3(64), 0, stream, out);
    hipLaunchKernelGGL(stats_kernel, dim3(B), dim3(BLOCK), 0, stream,
                       y_pred, y_true, ws);
    hipLaunchKernelGGL(epilogue_kernel, dim3(B), dim3(BLOCK), 0, stream,
                       y_pred, y_true, Lambda, ws, out, inv_total);
}

// Round 4
// 225.640 us; speedup vs baseline: 1.0410x; 1.0410x over previous
//
#include <hip/hip_runtime.h>
#include <math.h>

// B=2048, N=8192, fp32. Fused kernel, one block per row, 256 threads.
// R4 = R3 resubmit (container-level infra failure, kernel audit clean):
// (a) Newton's per-iter cross-lane reduce was 12 dependent ds_bpermute ops
// (~2000cy/iter, ~40us tail per R2's occupancy algebra) -> 6-step DPP reduce
// (~50cy) + bin counts hoisted to registers. (b) out+1 misalignment forced
// scalar stores -> per-wave chunks + lane-rotate shfl -> aligned float4 stores.
#define N_COLS 8192
#define BLOCK  256
#define NW     4                    // waves per block
#define CHUNK  (N_COLS / NW)        // 2048 elements per wave
#define KG     (CHUNK / 256)        // 8 float4 groups per lane
#define NBINS  1024
#define BPL    (NBINS / 64)         // 16 bins per lane in the Newton wave

// d_out[0] must be zeroed every call (harness re-poisons to 0xAA).
__global__ void zero_out_kernel(float* out) {
    if (threadIdx.x == 0 && blockIdx.x == 0) out[0] = 0.0f;
}

// Canonical gfx9 wave64 sum via DPP: row_shr 1/2/4/8 then row_bcast15 (rows
// 1,3) and row_bcast31 (rows 2,3); total lands in lane 63, readlane -> uniform.
// update_dpp(old=0,...,bound_ctrl=1): invalid-fetch and masked lanes add 0.
__device__ __forceinline__ float wave64_sum_dpp(float x) {
    union fi { float f; int i; };
    fi v, t; v.f = x;
    t.i = __builtin_amdgcn_update_dpp(0, v.i, 0x111, 0xf, 0xf, true); v.f += t.f; // row_shr:1
    t.i = __builtin_amdgcn_update_dpp(0, v.i, 0x112, 0xf, 0xf, true); v.f += t.f; // row_shr:2
    t.i = __builtin_amdgcn_update_dpp(0, v.i, 0x114, 0xf, 0xf, true); v.f += t.f; // row_shr:4
    t.i = __builtin_amdgcn_update_dpp(0, v.i, 0x118, 0xf, 0xf, true); v.f += t.f; // row_shr:8
    t.i = __builtin_amdgcn_update_dpp(0, v.i, 0x142, 0xa, 0xf, true); v.f += t.f; // row_bcast:15
    t.i = __builtin_amdgcn_update_dpp(0, v.i, 0x143, 0xc, 0xf, true); v.f += t.f; // row_bcast:31
    v.i = __builtin_amdgcn_readlane(v.i, 63);
    return v.f;
}

__global__ __launch_bounds__(BLOCK) void custom_loss_kernel(
        const float* __restrict__ y_pred,
        const float* __restrict__ y_true,
        const float* __restrict__ Lambda,
        float* __restrict__ out,      // out[0]=loss, out[1..]=updated_Lambda
        float inv_total) {
    __shared__ unsigned int s_hist[NBINS];   // count-only histogram of r
    __shared__ float s_wmax[NW];
    __shared__ float s_part[NW];
    __shared__ float s_bcast[2];             // {beta, inv_qmax}

    const int row  = blockIdx.x;
    const int tid  = threadIdx.x;
    const int lane = tid & 63;
    const int wid  = tid >> 6;
    const size_t base = (size_t)row * N_COLS;
    // per-wave contiguous chunk: element e = wid*CHUNK + k*256 + lane*4 + c
    const int f4base = wid * (CHUNK / 4) + lane;       // float4 index, + k*64
    const float4* yp4 = (const float4*)(y_pred + base);  // rows are 32KB-aligned
    const float4* yt4 = (const float4*)(y_true + base);

    // ---- pass 1: residuals in registers, local max ----
    float4 r[KG];
    float rmax = 0.0f;
    #pragma unroll
    for (int k = 0; k < KG; ++k) {
        const int g = f4base + k * 64;       // coalesced float4 within wave
        float4 a = yt4[g];
        float4 b = yp4[g];
        float4 rv;
        rv.x = fabsf(a.x - b.x); rv.y = fabsf(a.y - b.y);
        rv.z = fabsf(a.z - b.z); rv.w = fabsf(a.w - b.w);
        r[k] = rv;
        rmax = fmaxf(rmax, fmaxf(fmaxf(rv.x, rv.y), fmaxf(rv.z, rv.w)));
    }
    #pragma unroll
    for (int m = 32; m >= 1; m >>= 1) rmax = fmaxf(rmax, __shfl_xor(rmax, m, 64));
    if (lane == 0) s_wmax[wid] = rmax;
    #pragma unroll
    for (int i = 0; i < NBINS / BLOCK; ++i) s_hist[tid + i * BLOCK] = 0u;
    __syncthreads();                          // hist zeroed + s_wmax visible
    rmax = fmaxf(fmaxf(s_wmax[0], s_wmax[1]), fmaxf(s_wmax[2], s_wmax[3]));
    rmax = fmaxf(rmax, 1e-8f);

    // ---- pass 2: histogram of r (count only; bin centers are the proxy) ----
    const float hscale = (float)NBINS / rmax;
    #pragma unroll
    for (int k = 0; k < KG; ++k) {
        unsigned bx = min((unsigned)(r[k].x * hscale), (unsigned)(NBINS - 1));
        unsigned by = min((unsigned)(r[k].y * hscale), (unsigned)(NBINS - 1));
        unsigned bz = min((unsigned)(r[k].z * hscale), (unsigned)(NBINS - 1));
        unsigned bw = min((unsigned)(r[k].w * hscale), (unsigned)(NBINS - 1));
        atomicAdd(&s_hist[bx], 1u);
        atomicAdd(&s_hist[by], 1u);
        atomicAdd(&s_hist[bz], 1u);
        atomicAdd(&s_hist[bw], 1u);
    }
    __syncthreads();                          // histogram complete

    // ---- prefetch Lambda: 64MB stream overlaps the Newton solve below ----
    const float4* lam4 = (const float4*)(Lambda + base);
    float4 lam[KG];
    #pragma unroll
    for (int k = 0; k < KG; ++k) lam[k] = lam4[f4base + k * 64];

    // ---- Newton on the 1024-bin histogram: wave 0 only ----
    if (wid == 0) {
        // bin counts are iteration-invariant: hoist to registers once
        float nreg[BPL];
        #pragma unroll
        for (int k = 0; k < BPL; ++k) nreg[k] = (float)s_hist[lane + 64 * k];

        float eps = rmax / (logf(2.0f * (float)N_COLS) + 1e-8f);
        const float binw = rmax * (1.0f / (float)NBINS);
        const float sc2  = 0.5f / (float)N_COLS;   // 2^-14 exact
        for (int it = 0; it < 20; ++it) {
            const float inv_eps = __builtin_amdgcn_rcpf(fmaxf(eps, 1e-8f));
            const float d   = binw * inv_eps;       // per-bin u step
            const float d64 = 64.0f * d;            // per-k u step (this lane)
            float u  = ((float)lane + 0.5f) * d;    // u of bin 'lane'
            float e  = __expf(u);                   // running exp(+u)
            float ei = __expf(-u);                  // running exp(-u)
            const float E  = __expf(d64);           // geometric ratios
            const float Ei = __expf(-d64);
            float fs = 0.0f, gs = 0.0f;     // sum n*(e-ei), sum n*(e+ei)*u
            #pragma unroll
            for (int k = 0; k < BPL; ++k) {
                const float n = nreg[k];
                fs = fmaf(n, e - ei, fs);
                gs = fmaf(n * (e + ei), u, gs);
                e *= E; ei *= Ei; u += d64;
            }
            fs = wave64_sum_dpp(fs);                // ~50cy vs ~1400cy butterfly
            gs = wave64_sum_dpp(gs);
            float val  = fmaf(fs, sc2, -1.0f);          // mean(sinh)-1
            float grad = -(gs * sc2) * inv_eps;         // mean(cosh*(-u/eps))
            float delta = val * __builtin_amdgcn_rcpf(grad - 1e-8f);
            eps -= delta;
            if (fabsf(delta) <= 1e-5f * eps) break;     // wave-uniform
        }
        eps = fmaxf(eps, 1e-8f);
        const float beta = 1.0f / (eps + 1e-6f);
        const float um = beta * rmax;                   // qmax = sinh(beta*rmax)
        const float qmax = 0.5f * (__expf(um) - __expf(-um));
        if (lane == 0) {
            s_bcast[0] = beta;
            s_bcast[1] = 1.0f / (qmax + 1e-20f);
        }
    }
    __syncthreads();
    const float beta     = s_bcast[0];
    const float inv_qmax = s_bcast[1];

    // ---- epilogue: q=sinh(beta*r), EMA update, loss partial ----
    float4 uL[KG];
    float s_loss = 0.0f;
    #define EMA1(RR, LL, DST) { \
        float u_ = beta * (RR); \
        float q_ = 0.5f * (__expf(u_) - __expf(-u_)); \
        float li_ = fmaf(0.9f, q_ * inv_qmax, 0.1f);   /* PHI, 1-PHI */ \
        (DST) = fmaf(0.99f, (LL), 0.1f * li_);         /* GAMMA, ETA */ \
        float t_ = (DST) * (RR); \
        s_loss = fmaf(t_, t_, s_loss); }
    #pragma unroll
    for (int k = 0; k < KG; ++k) {
        EMA1(r[k].x, lam[k].x, uL[k].x);
        EMA1(r[k].y, lam[k].y, uL[k].y);
        EMA1(r[k].z, lam[k].z, uL[k].z);
        EMA1(r[k].w, lam[k].w, uL[k].w);
    }
    #undef EMA1

    // ---- aligned stores: out+1 is 4B-aligned, so each wave-chunk stores
    // elements [3..2046] as float4 {own.c3, next-lane c0,c1,c2} at 16B-aligned
    // addresses; elements {0,1,2,2047} of the chunk go scalar. "next lane" for
    // lane 63 is lane 0 of the NEXT k-group, so source lane 0 swaps in uL[k+1].
    float* outw = out + 1 + base + (size_t)wid * CHUNK;  // chunk element base
    const int src = (lane + 1) & 63;                     // rotate-by-1
    #pragma unroll
    for (int k = 0; k < KG; ++k) {
        const float4 cur = uL[k];
        const float4 nxt = uL[(k + 1) & (KG - 1)];  // k=KG-1 value masked below
        float sx = (lane == 0) ? nxt.x : cur.x;
        float sy = (lane == 0) ? nxt.y : cur.y;
        float sz = (lane == 0) ? nxt.z : cur.z;
        float4 vv;
        vv.x = cur.w;
        vv.y = __shfl(sx, src, 64);
        vv.z = __shfl(sy, src, 64);
        vv.w = __shfl(sz, src, 64);
        if (!(k == KG - 1 && lane == 63)) {
            // addr = out + base + wid*CHUNK + k*256 + lane*4 + 4 : 16B-aligned
            *(float4*)(outw + k * 256 + lane * 4 + 3) = vv;
        }
    }
    if (lane == 0) {            // chunk elements 0,1,2
        outw[0] = uL[0].x; outw[1] = uL[0].y; outw[2] = uL[0].z;
    }
    if (lane == 63) outw[CHUNK - 1] = uL[KG - 1].w;   // chunk element 2047

    // ---- loss reduction ----
    #pragma unroll
    for (int m = 32; m >= 1; m >>= 1) s_loss += __shfl_xor(s_loss, m, 64);
    if (lane == 0) s_part[wid] = s_loss;
    __syncthreads();
    if (tid == 0) {
        float tot = (s_part[0] + s_part[1]) + (s_part[2] + s_part[3]);
        atomicAdd(out, tot * inv_total);
    }
}

extern "C" void kernel_launch(void* const* d_in, const int* in_sizes, int n_in,
                              void* d_out, int out_size, void* d_ws, size_t ws_size,
                              hipStream_t stream) {
    const float* y_pred = (const float*)d_in[0];
    const float* y_true = (const float*)d_in[1];
    const float* Lambda = (const float*)d_in[2];
    float* out = (float*)d_out;

    const int total = in_sizes[0];            // B * N
    const int B = total / N_COLS;
    const float inv_total = 1.0f / (float)total;

    hipLaunchKernelGGL(zero_out_kernel, dim3(1), dim3(64), 0, stream, out);
    hipLaunchKernelGGL(custom_loss_kernel, dim3(B), dim3(BLOCK), 0, stream,
                       y_pred, y_true, Lambda, out, inv_total);
}

// Round 5
// 222.466 us; speedup vs baseline: 1.0559x; 1.0143x over previous
//
#include <hip/hip_runtime.h>
#include <math.h>

// B=2048, N=8192, fp32. Fused kernel, one block per row, 256 threads.
// R5: spill elimination. R1/R4 allocated only 60-64 VGPR against ~100 live
// (r[8]+lam[8]+misc) because default launch_bounds targets 8 waves/SIMD ->
// compiler spilled ~40 regs to scratch per thread (~160MB grid-wide round
// trip at phase boundaries). __launch_bounds__(256,4) caps occupancy at
// 4 blocks/CU -> 128 VGPR budget -> zero spill. Store path reverted to
// immediate scalar stores (WRITE_SIZE proved them HBM-neutral; the R4
// aligned-store trick added 32 live regs for nothing). DPP reductions kept.
#define N_COLS 8192
#define BLOCK  256
#define NW     4                    // waves per block
#define F4PT   (N_COLS / BLOCK / 4) // float4 groups per thread = 8
#define NBINS  1024
#define BPL    (NBINS / 64)         // 16 bins per lane in the Newton wave

// d_out[0] must be zeroed every call (harness re-poisons to 0xAA).
__global__ void zero_out_kernel(float* out) {
    if (threadIdx.x == 0 && blockIdx.x == 0) out[0] = 0.0f;
}

// Canonical gfx9 wave64 reduce via DPP: row_shr 1/2/4/8, row_bcast15 (rows
// 1,3), row_bcast31 (rows 2,3); total lands in lane 63, readlane -> uniform.
// update_dpp(old=0,...,bound_ctrl=1): invalid/masked lanes contribute identity.
__device__ __forceinline__ float wave64_sum_dpp(float x) {
    union fi { float f; int i; };
    fi v, t; v.f = x;
    t.i = __builtin_amdgcn_update_dpp(0, v.i, 0x111, 0xf, 0xf, true); v.f += t.f;
    t.i = __builtin_amdgcn_update_dpp(0, v.i, 0x112, 0xf, 0xf, true); v.f += t.f;
    t.i = __builtin_amdgcn_update_dpp(0, v.i, 0x114, 0xf, 0xf, true); v.f += t.f;
    t.i = __builtin_amdgcn_update_dpp(0, v.i, 0x118, 0xf, 0xf, true); v.f += t.f;
    t.i = __builtin_amdgcn_update_dpp(0, v.i, 0x142, 0xa, 0xf, true); v.f += t.f;
    t.i = __builtin_amdgcn_update_dpp(0, v.i, 0x143, 0xc, 0xf, true); v.f += t.f;
    v.i = __builtin_amdgcn_readlane(v.i, 63);
    return v.f;
}

__device__ __forceinline__ float wave64_max_dpp(float x) {
    union fi { float f; int i; };
    fi v, t; v.f = x;
    t.i = __builtin_amdgcn_update_dpp(0, v.i, 0x111, 0xf, 0xf, true); v.f = fmaxf(v.f, t.f);
    t.i = __builtin_amdgcn_update_dpp(0, v.i, 0x112, 0xf, 0xf, true); v.f = fmaxf(v.f, t.f);
    t.i = __builtin_amdgcn_update_dpp(0, v.i, 0x114, 0xf, 0xf, true); v.f = fmaxf(v.f, t.f);
    t.i = __builtin_amdgcn_update_dpp(0, v.i, 0x118, 0xf, 0xf, true); v.f = fmaxf(v.f, t.f);
    t.i = __builtin_amdgcn_update_dpp(0, v.i, 0x142, 0xa, 0xf, true); v.f = fmaxf(v.f, t.f);
    t.i = __builtin_amdgcn_update_dpp(0, v.i, 0x143, 0xc, 0xf, true); v.f = fmaxf(v.f, t.f);
    v.i = __builtin_amdgcn_readlane(v.i, 63);
    return v.f;
}
// NOTE on bound_ctrl with max: invalid fetches return 0; residuals are >=0 so
// identity-0 is safe for the max reduction here (rmax >= 0 always).

__global__ __launch_bounds__(BLOCK, 4) void custom_loss_kernel(
        const float* __restrict__ y_pred,
        const float* __restrict__ y_true,
        const float* __restrict__ Lambda,
        float* __restrict__ out,      // out[0]=loss, out[1..]=updated_Lambda
        float inv_total) {
    __shared__ unsigned int s_hist[NBINS];   // count-only histogram of r
    __shared__ float s_wmax[NW];
    __shared__ float s_part[NW];
    __shared__ float s_bcast[2];             // {beta, inv_qmax}

    const int row  = blockIdx.x;
    const int tid  = threadIdx.x;
    const int lane = tid & 63;
    const int wid  = tid >> 6;
    const size_t base = (size_t)row * N_COLS;
    const float4* yp4 = (const float4*)(y_pred + base);  // rows are 32KB-aligned
    const float4* yt4 = (const float4*)(y_true + base);

    // ---- pass 1: residuals in registers (float4 layout), local max ----
    float4 r[F4PT];
    float rmax = 0.0f;
    #pragma unroll
    for (int j = 0; j < F4PT; ++j) {
        const int g = j * BLOCK + tid;       // coalesced float4
        float4 a = yt4[g];
        float4 b = yp4[g];
        float4 rv;
        rv.x = fabsf(a.x - b.x); rv.y = fabsf(a.y - b.y);
        rv.z = fabsf(a.z - b.z); rv.w = fabsf(a.w - b.w);
        r[j] = rv;
        rmax = fmaxf(rmax, fmaxf(fmaxf(rv.x, rv.y), fmaxf(rv.z, rv.w)));
    }
    rmax = wave64_max_dpp(rmax);
    if (lane == 0) s_wmax[wid] = rmax;
    #pragma unroll
    for (int i = 0; i < NBINS / BLOCK; ++i) s_hist[tid + i * BLOCK] = 0u;
    __syncthreads();                          // hist zeroed + s_wmax visible
    rmax = fmaxf(fmaxf(s_wmax[0], s_wmax[1]), fmaxf(s_wmax[2], s_wmax[3]));
    rmax = fmaxf(rmax, 1e-8f);

    // ---- pass 2: histogram of r (count only; bin centers are the proxy) ----
    const float hscale = (float)NBINS / rmax;
    #pragma unroll
    for (int j = 0; j < F4PT; ++j) {
        unsigned bx = min((unsigned)(r[j].x * hscale), (unsigned)(NBINS - 1));
        unsigned by = min((unsigned)(r[j].y * hscale), (unsigned)(NBINS - 1));
        unsigned bz = min((unsigned)(r[j].z * hscale), (unsigned)(NBINS - 1));
        unsigned bw = min((unsigned)(r[j].w * hscale), (unsigned)(NBINS - 1));
        atomicAdd(&s_hist[bx], 1u);
        atomicAdd(&s_hist[by], 1u);
        atomicAdd(&s_hist[bz], 1u);
        atomicAdd(&s_hist[bw], 1u);
    }
    __syncthreads();                          // histogram complete

    // ---- prefetch Lambda: 64MB stream overlaps the Newton solve below ----
    const float4* lam4 = (const float4*)(Lambda + base);
    float4 lam[F4PT];
    #pragma unroll
    for (int j = 0; j < F4PT; ++j) lam[j] = lam4[j * BLOCK + tid];

    // ---- Newton on the 1024-bin histogram: wave 0 only ----
    if (wid == 0) {
        // bin counts are iteration-invariant: hoist to registers once
        float nreg[BPL];
        #pragma unroll
        for (int k = 0; k < BPL; ++k) nreg[k] = (float)s_hist[lane + 64 * k];

        float eps = rmax / (logf(2.0f * (float)N_COLS) + 1e-8f);
        const float binw = rmax * (1.0f / (float)NBINS);
        const float sc2  = 0.5f / (float)N_COLS;   // 2^-14 exact
        for (int it = 0; it < 20; ++it) {
            const float inv_eps = __builtin_amdgcn_rcpf(fmaxf(eps, 1e-8f));
            const float d   = binw * inv_eps;       // per-bin u step
            const float d64 = 64.0f * d;            // per-k u step (this lane)
            float u  = ((float)lane + 0.5f) * d;    // u of bin 'lane'
            float e  = __expf(u);                   // running exp(+u)
            float ei = __expf(-u);                  // running exp(-u)
            const float E  = __expf(d64);           // geometric ratios
            const float Ei = __expf(-d64);
            float fs = 0.0f, gs = 0.0f;     // sum n*(e-ei), sum n*(e+ei)*u
            #pragma unroll
            for (int k = 0; k < BPL; ++k) {
                const float n = nreg[k];
                fs = fmaf(n, e - ei, fs);
                gs = fmaf(n * (e + ei), u, gs);
                e *= E; ei *= Ei; u += d64;
            }
            fs = wave64_sum_dpp(fs);
            gs = wave64_sum_dpp(gs);
            float val  = fmaf(fs, sc2, -1.0f);          // mean(sinh)-1
            float grad = -(gs * sc2) * inv_eps;         // mean(cosh*(-u/eps))
            float delta = val * __builtin_amdgcn_rcpf(grad - 1e-8f);
            eps -= delta;
            if (fabsf(delta) <= 1e-5f * eps) break;     // wave-uniform
        }
        eps = fmaxf(eps, 1e-8f);
        const float beta = 1.0f / (eps + 1e-6f);
        const float um = beta * rmax;                   // qmax = sinh(beta*rmax)
        const float qmax = 0.5f * (__expf(um) - __expf(-um));
        if (lane == 0) {
            s_bcast[0] = beta;
            s_bcast[1] = 1.0f / (qmax + 1e-20f);
        }
    }
    __syncthreads();
    const float beta     = s_bcast[0];
    const float inv_qmax = s_bcast[1];

    // ---- epilogue: q=sinh(beta*r), EMA update, immediate store, loss ----
    float* outw = out + 1 + base;   // 4B-aligned only -> scalar stores (HBM-
                                    // neutral per WRITE_SIZE; HW coalesces)
    float s_loss = 0.0f;
    #pragma unroll
    for (int j = 0; j < F4PT; ++j) {
        const int g = j * BLOCK + tid;
        float rr[4] = {r[j].x, r[j].y, r[j].z, r[j].w};
        float LL[4] = {lam[j].x, lam[j].y, lam[j].z, lam[j].w};
        #pragma unroll
        for (int c = 0; c < 4; ++c) {
            float u  = beta * rr[c];
            float q  = 0.5f * (__expf(u) - __expf(-u));
            float lam_it = fmaf(0.9f, q * inv_qmax, 0.1f);  // PHI, 1-PHI
            float uL = fmaf(0.99f, LL[c], 0.1f * lam_it);   // GAMMA, ETA
            outw[(size_t)g * 4 + c] = uL;
            float t = uL * rr[c];
            s_loss = fmaf(t, t, s_loss);
        }
    }
    s_loss = wave64_sum_dpp(s_loss);
    if (lane == 0) s_part[wid] = s_loss;
    __syncthreads();
    if (tid == 0) {
        float tot = (s_part[0] + s_part[1]) + (s_part[2] + s_part[3]);
        atomicAdd(out, tot * inv_total);
    }
}

extern "C" void kernel_launch(void* const* d_in, const int* in_sizes, int n_in,
                              void* d_out, int out_size, void* d_ws, size_t ws_size,
                              hipStream_t stream) {
    const float* y_pred = (const float*)d_in[0];
    const float* y_true = (const float*)d_in[1];
    const float* Lambda = (const float*)d_in[2];
    float* out = (float*)d_out;

    const int total = in_sizes[0];            // B * N
    const int B = total / N_COLS;
    const float inv_total = 1.0f / (float)total;

    hipLaunchKernelGGL(zero_out_kernel, dim3(1), dim3(64), 0, stream, out);
    hipLaunchKernelGGL(custom_loss_kernel, dim3(B), dim3(BLOCK), 0, stream,
                       y_pred, y_true, Lambda, out, inv_total);
}